// Round 1
// baseline (941.597 us; speedup 1.0000x reference)
//
#include <hip/hip_runtime.h>
#include <hip/hip_bf16.h>

// ---------------------------------------------------------------------------
// CGNN: 2 layers of { m = h[src]*e ; s = segment_sum(m,dst) ; deg-mean ;
//                     [h, h_N] @ W + b (+ relu on layer 1) }
// Baseline strategy: fp32 atomicAdd scatter aggregation (wave = 1 edge,
// lane = 1 feature), degree computed once, dense layers with W staged in LDS.
// ---------------------------------------------------------------------------

#define F 64  // feature width for both h (layer1 in) and h1 (layer2 in)

__global__ __launch_bounds__(256) void degree_kernel(
    const int* __restrict__ dst, float* __restrict__ deg, int n_edges)
{
    int i = blockIdx.x * blockDim.x + threadIdx.x;
    if (i < n_edges) atomicAdd(&deg[dst[i]], 1.0f);
}

// One wave (64 lanes) per edge; lane = feature index. Coalesced 256B gather
// of h[src], scaled by edge scalar, atomicAdd scatter into s[dst].
__global__ __launch_bounds__(256) void aggregate_kernel(
    const float* __restrict__ h, const float* __restrict__ ef,
    const int* __restrict__ src, const int* __restrict__ dst,
    float* __restrict__ s, int n_edges)
{
    int gid  = blockIdx.x * blockDim.x + threadIdx.x;
    int edge = gid >> 6;
    int lane = gid & 63;
    if (edge >= n_edges) return;
    int   sv = src[edge];
    int   dv = dst[edge];
    float ev = ef[edge];
    float v  = h[(size_t)sv * F + lane] * ev;
    atomicAdd(&s[(size_t)dv * F + lane], v);
}

// out[n, j] = act( sum_k  x[n,k] * W[k,j]  + b[j] ),
// where x = concat(h[n,:], s[n,:]/max(deg,1)) of width 128.
// W staged in LDS; per-block node rows staged in LDS.
template <int OUT, bool RELU>
__global__ __launch_bounds__(256) void linear_kernel(
    const float* __restrict__ hin, const float* __restrict__ s,
    const float* __restrict__ deg, const float* __restrict__ W,
    const float* __restrict__ b, float* __restrict__ out, int n_nodes)
{
    constexpr int NPB = 256 / OUT;  // nodes per block
    __shared__ float Ws[128 * OUT];
    __shared__ float xin[NPB][128];

    const int tid = threadIdx.x;
    // stage W (128 x OUT, row-major) into LDS
    for (int i = tid; i < 128 * OUT; i += 256) Ws[i] = W[i];

    const int node0 = blockIdx.x * NPB;

    // stage input rows: first half = h, second half = s / max(deg,1)
    for (int i = tid; i < NPB * F; i += 256) {
        int ln = i / F, k = i % F;
        int node = node0 + ln;
        float hv = 0.f;
        if (node < n_nodes) hv = hin[(size_t)node * F + k];
        xin[ln][k] = hv;
    }
    for (int i = tid; i < NPB * F; i += 256) {
        int ln = i / F, k = i % F;
        int node = node0 + ln;
        float svv = 0.f;
        if (node < n_nodes) {
            float dg = deg[node];
            dg = dg > 1.f ? dg : 1.f;
            svv = s[(size_t)node * F + k] / dg;
        }
        xin[ln][F + k] = svv;
    }
    __syncthreads();

    const int ln   = tid / OUT;
    const int j    = tid % OUT;
    const int node = node0 + ln;
    if (node >= n_nodes) return;

    float acc = b[j];
#pragma unroll 16
    for (int k = 0; k < 128; ++k) acc += xin[ln][k] * Ws[k * OUT + j];
    if (RELU) acc = acc > 0.f ? acc : 0.f;
    out[(size_t)node * OUT + j] = acc;
}

extern "C" void kernel_launch(void* const* d_in, const int* in_sizes, int n_in,
                              void* d_out, int out_size, void* d_ws, size_t ws_size,
                              hipStream_t stream)
{
    const float* in_feat   = (const float*)d_in[0];
    const float* edge_feat = (const float*)d_in[1];
    const int*   src       = (const int*)d_in[2];
    const int*   dst       = (const int*)d_in[3];
    const float* W1        = (const float*)d_in[4];
    const float* b1        = (const float*)d_in[5];
    const float* W2        = (const float*)d_in[6];
    const float* b2        = (const float*)d_in[7];
    float*       out       = (float*)d_out;

    const int n_nodes = in_sizes[0] / F;
    const int n_edges = in_sizes[2];

    // workspace layout (floats)
    float* ws  = (float*)d_ws;
    float* deg = ws;                       // [131072]  (padded n_nodes)
    float* s   = ws + 131072;              // [n_nodes * 64]
    float* h1  = s + (size_t)n_nodes * F;  // [n_nodes * 64]

    const size_t s_bytes = (size_t)n_nodes * F * sizeof(float);

    // zero deg + s (contiguous)
    hipMemsetAsync(deg, 0, 131072 * sizeof(float) + s_bytes, stream);

    const int eb = 256;
    const int deg_grid = (n_edges + eb - 1) / eb;
    degree_kernel<<<deg_grid, eb, 0, stream>>>(dst, deg, n_edges);

    const long long ethreads = (long long)n_edges * 64;
    const int agg_grid = (int)((ethreads + eb - 1) / eb);

    // ---- layer 1 ----
    aggregate_kernel<<<agg_grid, eb, 0, stream>>>(in_feat, edge_feat, src, dst, s, n_edges);
    {
        const int NPB = 256 / 64;
        const int grid = (n_nodes + NPB - 1) / NPB;
        linear_kernel<64, true><<<grid, 256, 0, stream>>>(in_feat, s, deg, W1, b1, h1, n_nodes);
    }

    // ---- layer 2 ----
    hipMemsetAsync(s, 0, s_bytes, stream);
    aggregate_kernel<<<agg_grid, eb, 0, stream>>>(h1, edge_feat, src, dst, s, n_edges);
    {
        const int NPB = 256 / 32;
        const int grid = (n_nodes + NPB - 1) / NPB;
        linear_kernel<32, false><<<grid, 256, 0, stream>>>(h1, s, deg, W2, b2, out, n_nodes);
    }
}

// Round 2
// 762.744 us; speedup vs baseline: 1.2345x; 1.2345x over previous
//
#include <hip/hip_runtime.h>
#include <hip/hip_bf16.h>

// ---------------------------------------------------------------------------
// CGNN: 2 layers of { m = h[src]*e ; s = segment_mean(m,dst) ;
//                     [h, h_N] @ W + b (+ relu on layer 1) }
// Round 1: CSR-by-dst aggregation (built once, reused by both layers).
//  - count_kernel: int histogram of dst
//  - offsets_kernel: block scan + global atomic base -> off/cursor/invdeg
//  - scatter_kernel: rec[pos] = (src, edge_feat) packed, pos via cursor atomic
//  - agg_csr_kernel: wave per node, lane = feature, register accumulate,
//    single write of s = acc * invdeg  (no feature atomics, 16x less write)
//  - linear_kernel: W in LDS, 32 nodes/block, k-outer/node-inner float4 reads
// ---------------------------------------------------------------------------

#define F 64

__global__ __launch_bounds__(256) void count_kernel(
    const int* __restrict__ dst, int* __restrict__ cnt, int n_edges)
{
    int i = blockIdx.x * blockDim.x + threadIdx.x;
    if (i < n_edges) atomicAdd(&cnt[dst[i]], 1);
}

// Block-level exclusive scan of cnt; global base via one atomicAdd per block.
// Range assignment order is non-deterministic but ranges are disjoint+valid.
__global__ __launch_bounds__(1024) void offsets_kernel(
    const int* __restrict__ cnt, int* __restrict__ off, int* __restrict__ cursor,
    float* __restrict__ invdeg, int n, int* __restrict__ gbase)
{
    __shared__ int wsum[16];
    __shared__ int bbase;
    const int tid = threadIdx.x;
    const int i = blockIdx.x * 1024 + tid;
    const int c = (i < n) ? cnt[i] : 0;

    // intra-wave inclusive scan
    int v = c;
    for (int d = 1; d < 64; d <<= 1) {
        int t = __shfl_up(v, d, 64);
        if ((tid & 63) >= d) v += t;
    }
    const int wid = tid >> 6;  // 16 waves
    if ((tid & 63) == 63) wsum[wid] = v;
    __syncthreads();

    if (tid < 16) {
        int t = wsum[tid];
        for (int d = 1; d < 16; d <<= 1) {
            int u = __shfl_up(t, d, 64);
            if (tid >= d) t += u;
        }
        wsum[tid] = t;  // inclusive wave-sum scan
        if (tid == 15) bbase = atomicAdd(gbase, t);
    }
    __syncthreads();

    const int waveoff = (wid > 0) ? wsum[wid - 1] : 0;
    const int excl = bbase + waveoff + (v - c);
    if (i < n) {
        off[i]    = excl;
        cursor[i] = excl;
        invdeg[i] = 1.0f / fmaxf((float)c, 1.0f);
    }
}

__global__ __launch_bounds__(256) void scatter_kernel(
    const int* __restrict__ src, const int* __restrict__ dst,
    const float* __restrict__ ef, int* __restrict__ cursor,
    int2* __restrict__ rec, int n_edges)
{
    int i = blockIdx.x * blockDim.x + threadIdx.x;
    if (i >= n_edges) return;
    const int d   = dst[i];
    const int pos = atomicAdd(&cursor[d], 1);
    rec[pos] = make_int2(src[i], __float_as_int(ef[i]));
}

// One wave per node, lane = feature. Registers accumulate; one store per node.
__global__ __launch_bounds__(256) void agg_csr_kernel(
    const float* __restrict__ h, const int2* __restrict__ rec,
    const int* __restrict__ off, const int* __restrict__ cnt,
    const float* __restrict__ invdeg, float* __restrict__ s, int n_nodes)
{
    const int gid  = blockIdx.x * 256 + threadIdx.x;
    const int node = gid >> 6;
    const int lane = gid & 63;
    if (node >= n_nodes) return;

    const int e0 = off[node];
    const int ec = cnt[node];
    float acc = 0.f;
    for (int e = e0; e < e0 + ec; ++e) {
        const int2 r = rec[e];                       // wave-uniform 8B load
        acc = fmaf(h[(size_t)r.x * F + lane], __int_as_float(r.y), acc);
    }
    s[(size_t)node * F + lane] = acc * invdeg[node];
}

// out[n,j] = act( sum_k x[n,k] * W[k,j] + b[j] ),  x = concat(h[n], s[n]).
// W staged in LDS once per block (32 nodes amortize it); k-outer/node-inner
// with float4 xin reads to cut LDS instruction count.
template <int OUT, bool RELU>
__global__ __launch_bounds__(256) void linear_kernel(
    const float* __restrict__ hin, const float* __restrict__ s,
    const float* __restrict__ W, const float* __restrict__ b,
    float* __restrict__ out, int n_nodes)
{
    constexpr int NPB = 32;          // nodes per block
    constexpr int NG  = 256 / OUT;   // groups of lanes (each group = OUT lanes)
    constexpr int NPG = NPB / NG;    // nodes per group
    __shared__ float Ws[128 * OUT];
    __shared__ float xin[NPB][128];

    const int tid = threadIdx.x;
    for (int i = tid; i < 128 * OUT; i += 256) Ws[i] = W[i];

    const int node0 = blockIdx.x * NPB;
    for (int i = tid; i < NPB * F; i += 256) {
        const int ln = i >> 6, k = i & 63;
        const int node = node0 + ln;
        float hv = 0.f, sv = 0.f;
        if (node < n_nodes) {
            hv = hin[(size_t)node * F + k];
            sv = s[(size_t)node * F + k];
        }
        xin[ln][k]     = hv;
        xin[ln][F + k] = sv;
    }
    __syncthreads();

    const int j     = tid % OUT;
    const int lbase = (tid / OUT) * NPG;
    const float bj  = b[j];
    float acc[NPG];
#pragma unroll
    for (int l = 0; l < NPG; ++l) acc[l] = bj;

    for (int k4 = 0; k4 < 32; ++k4) {
        const float w0 = Ws[(4 * k4 + 0) * OUT + j];
        const float w1 = Ws[(4 * k4 + 1) * OUT + j];
        const float w2 = Ws[(4 * k4 + 2) * OUT + j];
        const float w3 = Ws[(4 * k4 + 3) * OUT + j];
#pragma unroll
        for (int l = 0; l < NPG; ++l) {
            const float4 xv = *(const float4*)&xin[lbase + l][4 * k4];
            acc[l] = fmaf(xv.x, w0, acc[l]);
            acc[l] = fmaf(xv.y, w1, acc[l]);
            acc[l] = fmaf(xv.z, w2, acc[l]);
            acc[l] = fmaf(xv.w, w3, acc[l]);
        }
    }

#pragma unroll
    for (int l = 0; l < NPG; ++l) {
        const int node = node0 + lbase + l;
        if (node < n_nodes) {
            float v = acc[l];
            if (RELU) v = fmaxf(v, 0.f);
            out[(size_t)node * OUT + l == l ? (size_t)node * OUT + j : 0] = v; // placeholder avoided below
        }
    }
}

// NOTE: the store above is replaced by a correct simple form in a fixed
// duplicate to avoid any expression ambiguity.
template <int OUT, bool RELU>
__global__ __launch_bounds__(256) void linear_kernel2(
    const float* __restrict__ hin, const float* __restrict__ s,
    const float* __restrict__ W, const float* __restrict__ b,
    float* __restrict__ out, int n_nodes)
{
    constexpr int NPB = 32;
    constexpr int NG  = 256 / OUT;
    constexpr int NPG = NPB / NG;
    __shared__ float Ws[128 * OUT];
    __shared__ float xin[NPB][128];

    const int tid = threadIdx.x;
    for (int i = tid; i < 128 * OUT; i += 256) Ws[i] = W[i];

    const int node0 = blockIdx.x * NPB;
    for (int i = tid; i < NPB * F; i += 256) {
        const int ln = i >> 6, k = i & 63;
        const int node = node0 + ln;
        float hv = 0.f, sv = 0.f;
        if (node < n_nodes) {
            hv = hin[(size_t)node * F + k];
            sv = s[(size_t)node * F + k];
        }
        xin[ln][k]     = hv;
        xin[ln][F + k] = sv;
    }
    __syncthreads();

    const int j     = tid % OUT;
    const int lbase = (tid / OUT) * NPG;
    const float bj  = b[j];
    float acc[NPG];
#pragma unroll
    for (int l = 0; l < NPG; ++l) acc[l] = bj;

    for (int k4 = 0; k4 < 32; ++k4) {
        const float w0 = Ws[(4 * k4 + 0) * OUT + j];
        const float w1 = Ws[(4 * k4 + 1) * OUT + j];
        const float w2 = Ws[(4 * k4 + 2) * OUT + j];
        const float w3 = Ws[(4 * k4 + 3) * OUT + j];
#pragma unroll
        for (int l = 0; l < NPG; ++l) {
            const float4 xv = *(const float4*)&xin[lbase + l][4 * k4];
            acc[l] = fmaf(xv.x, w0, acc[l]);
            acc[l] = fmaf(xv.y, w1, acc[l]);
            acc[l] = fmaf(xv.z, w2, acc[l]);
            acc[l] = fmaf(xv.w, w3, acc[l]);
        }
    }

#pragma unroll
    for (int l = 0; l < NPG; ++l) {
        const int node = node0 + lbase + l;
        if (node < n_nodes) {
            float v = acc[l];
            if (RELU) v = fmaxf(v, 0.f);
            out[(size_t)node * OUT + j] = v;
        }
    }
}

extern "C" void kernel_launch(void* const* d_in, const int* in_sizes, int n_in,
                              void* d_out, int out_size, void* d_ws, size_t ws_size,
                              hipStream_t stream)
{
    const float* in_feat   = (const float*)d_in[0];
    const float* edge_feat = (const float*)d_in[1];
    const int*   src       = (const int*)d_in[2];
    const int*   dst       = (const int*)d_in[3];
    const float* W1        = (const float*)d_in[4];
    const float* b1        = (const float*)d_in[5];
    const float* W2        = (const float*)d_in[6];
    const float* b2        = (const float*)d_in[7];
    float*       out       = (float*)d_out;

    const int n_nodes = in_sizes[0] / F;
    const int n_edges = in_sizes[2];

    // workspace layout (in 4-byte elements), S = padded node stride
    const int S = 100352;  // >= n_nodes, multiple of 256
    int*   base_i = (int*)d_ws;
    int*   cnt    = base_i;            // [n_nodes]
    int*   gbase  = base_i + n_nodes;  // [1]
    int*   off    = base_i + 1 * S;    // [n_nodes]
    int*   cursor = base_i + 2 * S;    // [n_nodes]
    float* invdeg = (float*)(base_i + 3 * S);          // [n_nodes]
    int2*  rec    = (int2*)(base_i + 4 * S);           // [n_edges] (8B each)
    float* s      = (float*)(base_i + 4 * S + 2 * (size_t)n_edges);  // [n*64]
    float* h1     = s + (size_t)n_nodes * F;                          // [n*64]

    // zero cnt + gbase
    hipMemsetAsync(cnt, 0, ((size_t)n_nodes + 1) * sizeof(int), stream);

    const int eb = 256;
    const int egrid = (n_edges + eb - 1) / eb;
    count_kernel<<<egrid, eb, 0, stream>>>(dst, cnt, n_edges);

    const int sgrid = (n_nodes + 1023) / 1024;
    offsets_kernel<<<sgrid, 1024, 0, stream>>>(cnt, off, cursor, invdeg, n_nodes, gbase);

    scatter_kernel<<<egrid, eb, 0, stream>>>(src, dst, edge_feat, cursor, rec, n_edges);

    const int agrid = (int)(((size_t)n_nodes * 64 + 255) / 256);
    const int lgrid = (n_nodes + 31) / 32;

    // ---- layer 1 ----
    agg_csr_kernel<<<agrid, 256, 0, stream>>>(in_feat, rec, off, cnt, invdeg, s, n_nodes);
    linear_kernel2<64, true><<<lgrid, 256, 0, stream>>>(in_feat, s, W1, b1, h1, n_nodes);

    // ---- layer 2 ----
    agg_csr_kernel<<<agrid, 256, 0, stream>>>(h1, rec, off, cnt, invdeg, s, n_nodes);
    linear_kernel2<32, false><<<lgrid, 256, 0, stream>>>(h1, s, W2, b2, out, n_nodes);
}

// Round 3
// 422.107 us; speedup vs baseline: 2.2307x; 1.8070x over previous
//
#include <hip/hip_runtime.h>
#include <hip/hip_bf16.h>

// ---------------------------------------------------------------------------
// CGNN: 2 layers of { m = h[src]*e ; s = segment_mean(m,dst) ;
//                     [h, h_N] @ W + b (+ relu on layer 1) }
// Round 2:
//  - CSR-by-dst built once (count / scan / scatter), reused by both layers.
//  - agg_csr_kernel v2: wave per node, 4 edges in flight (16 lanes x float4
//    each), register accumulate, shfl_xor reduce, single float4 store.
//  - linear_sgpr_kernel: thread per node, acc[OUT] in VGPRs, x via float4
//    global loads (h-stream + s-stream), W/b wave-uniform -> s_load SGPR
//    broadcast. No LDS, no W redundancy in VMEM.
// ---------------------------------------------------------------------------

#define F 64

__global__ __launch_bounds__(256) void count_kernel(
    const int* __restrict__ dst, int* __restrict__ cnt, int n_edges)
{
    int i = blockIdx.x * blockDim.x + threadIdx.x;
    if (i < n_edges) atomicAdd(&cnt[dst[i]], 1);
}

// Block-level exclusive scan of cnt; global base via one atomicAdd per block.
__global__ __launch_bounds__(1024) void offsets_kernel(
    const int* __restrict__ cnt, int* __restrict__ off, int* __restrict__ cursor,
    float* __restrict__ invdeg, int n, int* __restrict__ gbase)
{
    __shared__ int wsum[16];
    __shared__ int bbase;
    const int tid = threadIdx.x;
    const int i = blockIdx.x * 1024 + tid;
    const int c = (i < n) ? cnt[i] : 0;

    int v = c;
    for (int d = 1; d < 64; d <<= 1) {
        int t = __shfl_up(v, d, 64);
        if ((tid & 63) >= d) v += t;
    }
    const int wid = tid >> 6;
    if ((tid & 63) == 63) wsum[wid] = v;
    __syncthreads();

    if (tid < 16) {
        int t = wsum[tid];
        for (int d = 1; d < 16; d <<= 1) {
            int u = __shfl_up(t, d, 64);
            if (tid >= d) t += u;
        }
        wsum[tid] = t;
        if (tid == 15) bbase = atomicAdd(gbase, t);
    }
    __syncthreads();

    const int waveoff = (wid > 0) ? wsum[wid - 1] : 0;
    const int excl = bbase + waveoff + (v - c);
    if (i < n) {
        off[i]    = excl;
        cursor[i] = excl;
        invdeg[i] = 1.0f / fmaxf((float)c, 1.0f);
    }
}

__global__ __launch_bounds__(256) void scatter_kernel(
    const int* __restrict__ src, const int* __restrict__ dst,
    const float* __restrict__ ef, int* __restrict__ cursor,
    int2* __restrict__ rec, int n_edges)
{
    int i = blockIdx.x * blockDim.x + threadIdx.x;
    if (i >= n_edges) return;
    const int d   = dst[i];
    const int pos = atomicAdd(&cursor[d], 1);
    rec[pos] = make_int2(src[i], __float_as_int(ef[i]));
}

// Wave per node. lane = 16*g + q: g = edge slot (4 edges in flight),
// q = feature quad (float4). Register accumulate, shfl_xor reduce over g.
__global__ __launch_bounds__(256) void agg_csr_kernel(
    const float* __restrict__ h, const int2* __restrict__ rec,
    const int* __restrict__ off, const int* __restrict__ cnt,
    const float* __restrict__ invdeg, float* __restrict__ s, int n_nodes)
{
    const int gid  = blockIdx.x * 256 + threadIdx.x;
    const int node = gid >> 6;
    const int lane = threadIdx.x & 63;
    if (node >= n_nodes) return;

    const int g = lane >> 4;   // 0..3
    const int q = lane & 15;   // 0..15

    const int e0 = off[node];
    const int ee = e0 + cnt[node];

    float ax = 0.f, ay = 0.f, az = 0.f, aw = 0.f;
    for (int e = e0 + g; e < ee; e += 4) {
        const int2  r  = rec[e];
        const float ev = __int_as_float(r.y);
        const float4 xv = *(const float4*)&h[(size_t)r.x * F + q * 4];
        ax = fmaf(xv.x, ev, ax);
        ay = fmaf(xv.y, ev, ay);
        az = fmaf(xv.z, ev, az);
        aw = fmaf(xv.w, ev, aw);
    }
    // reduce across the 4 edge-slot groups (lanes g=0..3 share q)
    ax += __shfl_xor(ax, 16); ay += __shfl_xor(ay, 16);
    az += __shfl_xor(az, 16); aw += __shfl_xor(aw, 16);
    ax += __shfl_xor(ax, 32); ay += __shfl_xor(ay, 32);
    az += __shfl_xor(az, 32); aw += __shfl_xor(aw, 32);

    if (g == 0) {
        const float id = invdeg[node];
        float4 r = make_float4(ax * id, ay * id, az * id, aw * id);
        *(float4*)&s[(size_t)node * F + q * 4] = r;
    }
}

// Thread per node. out[n,j] = act( sum_k x[n,k]*W[k,j] + b[j] ),
// x = concat(h[n,:], s[n,:]). W/b accesses are wave-uniform -> SGPR s_load.
template <int OUT, bool RELU>
__global__ __launch_bounds__(256) void linear_sgpr_kernel(
    const float* __restrict__ hin, const float* __restrict__ s,
    const float* __restrict__ W, const float* __restrict__ b,
    float* __restrict__ out, int n_nodes)
{
    const int node_raw = blockIdx.x * 256 + threadIdx.x;
    const int node = node_raw < n_nodes ? node_raw : n_nodes - 1;  // clamp: no divergence in body

    float acc[OUT];
#pragma unroll
    for (int j = 0; j < OUT; ++j) acc[j] = b[j];

    const float* __restrict__ hrow = hin + (size_t)node * F;
    const float* __restrict__ srow = s   + (size_t)node * F;

    for (int k4 = 0; k4 < F / 4; ++k4) {
        const float4 xh = *(const float4*)&hrow[k4 * 4];   // two independent
        const float4 xs = *(const float4*)&srow[k4 * 4];   // load streams
#pragma unroll
        for (int kk = 0; kk < 4; ++kk) {
            const int k = k4 * 4 + kk;
            const float xhk = ((const float*)&xh)[kk];
            const float xsk = ((const float*)&xs)[kk];
#pragma unroll
            for (int j = 0; j < OUT; ++j)
                acc[j] = fmaf(xhk, W[k * OUT + j], acc[j]);
#pragma unroll
            for (int j = 0; j < OUT; ++j)
                acc[j] = fmaf(xsk, W[(F + k) * OUT + j], acc[j]);
        }
    }

    if (node_raw < n_nodes) {
#pragma unroll
        for (int j = 0; j < OUT; ++j) {
            float v = acc[j];
            if (RELU) v = fmaxf(v, 0.f);
            out[(size_t)node * OUT + j] = v;
        }
    }
}

extern "C" void kernel_launch(void* const* d_in, const int* in_sizes, int n_in,
                              void* d_out, int out_size, void* d_ws, size_t ws_size,
                              hipStream_t stream)
{
    const float* in_feat   = (const float*)d_in[0];
    const float* edge_feat = (const float*)d_in[1];
    const int*   src       = (const int*)d_in[2];
    const int*   dst       = (const int*)d_in[3];
    const float* W1        = (const float*)d_in[4];
    const float* b1        = (const float*)d_in[5];
    const float* W2        = (const float*)d_in[6];
    const float* b2        = (const float*)d_in[7];
    float*       out       = (float*)d_out;

    const int n_nodes = in_sizes[0] / F;
    const int n_edges = in_sizes[2];

    // workspace layout (in 4-byte elements), S = padded node stride
    const int S = 100352;  // >= n_nodes, multiple of 256
    int*   base_i = (int*)d_ws;
    int*   cnt    = base_i;            // [n_nodes]
    int*   gbase  = base_i + n_nodes;  // [1]
    int*   off    = base_i + 1 * S;    // [n_nodes]
    int*   cursor = base_i + 2 * S;    // [n_nodes]
    float* invdeg = (float*)(base_i + 3 * S);                        // [n_nodes]
    int2*  rec    = (int2*)(base_i + 4 * S);                         // [n_edges]
    float* s      = (float*)(base_i + 4 * S + 2 * (size_t)n_edges);  // [n*64]
    float* h1     = s + (size_t)n_nodes * F;                         // [n*64]

    hipMemsetAsync(cnt, 0, ((size_t)n_nodes + 1) * sizeof(int), stream);

    const int eb = 256;
    const int egrid = (n_edges + eb - 1) / eb;
    count_kernel<<<egrid, eb, 0, stream>>>(dst, cnt, n_edges);

    const int sgrid = (n_nodes + 1023) / 1024;
    offsets_kernel<<<sgrid, 1024, 0, stream>>>(cnt, off, cursor, invdeg, n_nodes, gbase);

    scatter_kernel<<<egrid, eb, 0, stream>>>(src, dst, edge_feat, cursor, rec, n_edges);

    const int agrid = (int)(((size_t)n_nodes * 64 + 255) / 256);
    const int lgrid = (n_nodes + 255) / 256;

    // ---- layer 1 ----
    agg_csr_kernel<<<agrid, 256, 0, stream>>>(in_feat, rec, off, cnt, invdeg, s, n_nodes);
    linear_sgpr_kernel<64, true><<<lgrid, 256, 0, stream>>>(in_feat, s, W1, b1, h1, n_nodes);

    // ---- layer 2 ----
    agg_csr_kernel<<<agrid, 256, 0, stream>>>(h1, rec, off, cnt, invdeg, s, n_nodes);
    linear_sgpr_kernel<32, false><<<lgrid, 256, 0, stream>>>(h1, s, W2, b2, out, n_nodes);
}